// Round 16
// baseline (411.031 us; speedup 1.0000x reference)
//
#include <hip/hip_runtime.h>
#include <math.h>

#define Dv 1024
#define Ev 8
#define Hv 2816
#define Nv 4096
#define NKv 8192
#define CAPv 1280
#define TH2v 5632

typedef unsigned short u16;
typedef unsigned char u8;
typedef __attribute__((ext_vector_type(4))) float f32x4;
typedef __attribute__((ext_vector_type(4))) int i32x4;
typedef __attribute__((ext_vector_type(8))) int i32x8;
typedef __attribute__((ext_vector_type(4))) unsigned u32x4;

typedef const __attribute__((address_space(1))) void* as1_cvp;
typedef __attribute__((address_space(3))) void* as3_vp;

// f32 -> OCP e4m3fn, RNE, saturate to 448 (software fallback)
__device__ __forceinline__ unsigned f2e4(float f) {
  unsigned u = __float_as_uint(f);
  unsigned sgn = (u >> 24) & 0x80u;
  unsigned ax = u & 0x7FFFFFFFu;
  if (ax >= 0x43E00000u) return sgn | 0x7Eu;
  if (ax < 0x3C800000u) {
    int qv = (int)rintf(__uint_as_float(ax) * 512.f);
    return sgn | (unsigned)qv;
  }
  unsigned lsb = (ax >> 20) & 1u;
  unsigned rr = ax + 0x0007FFFFu + lsb;
  unsigned ee = rr >> 23;
  unsigned mm = (rr >> 20) & 7u;
  if (ee > 135u) return sgn | 0x7Eu;
  return sgn | ((ee - 120u) << 3) | mm;
}
// e4m3fn -> f32 (software fallback)
__device__ __forceinline__ float e42f(unsigned v) {
  unsigned s = (v & 0x80u) << 24, e = (v >> 3) & 15u, m = v & 7u;
  if (e) return __uint_as_float(s | ((e + 120u) << 23) | (m << 20));
  return __uint_as_float(__float_as_uint((float)m * 0.001953125f) | s);
}

// packed converters (HW when available)
__device__ __forceinline__ unsigned cvtpk4(float a, float b, float c, float d) {
#if __has_builtin(__builtin_amdgcn_cvt_pk_fp8_f32)
  int w = __builtin_amdgcn_cvt_pk_fp8_f32(a, b, 0, false);
  w = __builtin_amdgcn_cvt_pk_fp8_f32(c, d, w, true);
  return (unsigned)w;
#else
  return f2e4(a) | (f2e4(b) << 8) | (f2e4(c) << 16) | (f2e4(d) << 24);
#endif
}
__device__ __forceinline__ u8 f2e4h(float a) {
#if __has_builtin(__builtin_amdgcn_cvt_pk_fp8_f32)
  return (u8)(__builtin_amdgcn_cvt_pk_fp8_f32(a, a, 0, false) & 0xffu);
#else
  return (u8)f2e4(a);
#endif
}
__device__ __forceinline__ void dec16(const u8* p, float* o) {
  const unsigned* w = (const unsigned*)p;
#if __has_builtin(__builtin_amdgcn_cvt_pk_f32_fp8)
  #pragma unroll
  for (int j = 0; j < 4; ++j) {
    int x = (int)w[j];
    auto lo = __builtin_amdgcn_cvt_pk_f32_fp8(x, false);
    auto hi = __builtin_amdgcn_cvt_pk_f32_fp8(x, true);
    o[j*4+0] = lo[0]; o[j*4+1] = lo[1]; o[j*4+2] = hi[0]; o[j*4+3] = hi[1];
  }
#else
  #pragma unroll
  for (int j = 0; j < 4; ++j) {
    unsigned x = w[j];
    o[j*4+0] = e42f(x & 255u);
    o[j*4+1] = e42f((x >> 8) & 255u);
    o[j*4+2] = e42f((x >> 16) & 255u);
    o[j*4+3] = e42f((x >> 24) & 255u);
  }
#endif
}
__device__ __forceinline__ void dec4(unsigned x, float* o) {
#if __has_builtin(__builtin_amdgcn_cvt_pk_f32_fp8)
  auto lo = __builtin_amdgcn_cvt_pk_f32_fp8((int)x, false);
  auto hi = __builtin_amdgcn_cvt_pk_f32_fp8((int)x, true);
  o[0] = lo[0]; o[1] = lo[1]; o[2] = hi[0]; o[3] = hi[1];
#else
  o[0] = e42f(x & 255u); o[1] = e42f((x >> 8) & 255u);
  o[2] = e42f((x >> 16) & 255u); o[3] = e42f((x >> 24) & 255u);
#endif
}
__device__ __forceinline__ unsigned pack4(float4 v, float s) {
  return cvtpk4(v.x * s, v.y * s, v.z * s, v.w * s);
}
__device__ __forceinline__ void gload16(const void* g, void* l) {
  __builtin_amdgcn_global_load_lds((as1_cvp)g, (as3_vp)l, 16, 0, 0);
}

// ---------------- router ----------------
__global__ __launch_bounds__(256) void router_kernel(
    const float* __restrict__ x, const float* __restrict__ gw,
    int* __restrict__ tkidx, float* __restrict__ tkprob,
    float* __restrict__ red, float* __restrict__ outIdx)
{
  __shared__ float lred[17];
  int tid = threadIdx.x;
  if (tid < 17) lred[tid] = 0.f;
  __syncthreads();
  int wv = tid >> 6, ln = tid & 63;
  int n = blockIdx.x * 4 + wv;
  float a[8] = {0.f,0.f,0.f,0.f,0.f,0.f,0.f,0.f};
  const float* xr = x + (size_t)n * Dv;
  #pragma unroll
  for (int it = 0; it < 16; ++it) {
    int d = ln + it * 64;
    float xs = xr[d];
    float4 g0 = *(const float4*)(gw + (size_t)d * 8);
    float4 g1 = *(const float4*)(gw + (size_t)d * 8 + 4);
    a[0] += xs * g0.x; a[1] += xs * g0.y; a[2] += xs * g0.z; a[3] += xs * g0.w;
    a[4] += xs * g1.x; a[5] += xs * g1.y; a[6] += xs * g1.z; a[7] += xs * g1.w;
  }
  #pragma unroll
  for (int off = 32; off >= 1; off >>= 1) {
    #pragma unroll
    for (int e = 0; e < 8; ++e) a[e] += __shfl_xor(a[e], off, 64);
  }
  int i1 = 0; float v1 = a[0];
  #pragma unroll
  for (int e = 1; e < 8; ++e) if (a[e] > v1) { v1 = a[e]; i1 = e; }
  int i2 = -1; float v2 = -1e30f;
  #pragma unroll
  for (int e = 0; e < 8; ++e) if (e != i1 && a[e] > v2) { v2 = a[e]; i2 = e; }
  float Z = 0.f;
  #pragma unroll
  for (int e = 0; e < 8; ++e) Z += expf(a[e] - v1);
  float zlse = v1 + logf(Z);
  float t = expf(v2 - v1);
  float p1 = 1.f / (1.f + t);
  float p2 = t * p1;
  if (ln == 0) {
    tkidx[2*n] = i1; tkidx[2*n+1] = i2;
    tkprob[2*n] = p1; tkprob[2*n+1] = p2;
    outIdx[2*n] = (float)i1; outIdx[2*n+1] = (float)i2;
    #pragma unroll
    for (int e = 0; e < 8; ++e) atomicAdd(&lred[e], expf(a[e] - v1) / Z);
    atomicAdd(&lred[8 + i1], 1.f);
    atomicAdd(&lred[16], zlse * zlse);
  }
  __syncthreads();
  if (tid < 17) atomicAdd(&red[tid], lred[tid]);
}

// ---------------- exact stable rank + counts + aux ----------------
__global__ __launch_bounds__(256) void rank_kernel(const int* __restrict__ tgt,
    int* __restrict__ keep, int* __restrict__ dstNK, int* __restrict__ cnt,
    const float* __restrict__ red, float* __restrict__ outAux)
{
  __shared__ int hist[256][8];
  int t = threadIdx.x;
  int h[8] = {0,0,0,0,0,0,0,0};
  int base = t * 32;
  for (int j = 0; j < 32; ++j) h[tgt[base + j]]++;
  for (int e = 0; e < 8; ++e) hist[t][e] = h[e];
  __syncthreads();
  if (t < 8) {
    int run = 0;
    for (int tt = 0; tt < 256; ++tt) { int v = hist[tt][t]; hist[tt][t] = run; run += v; }
    cnt[t] = run < CAPv ? run : CAPv;
  }
  if (t == 0) {
    float bl = 0.f;
    for (int e = 0; e < 8; ++e) bl += (red[e] / (float)Nv) * (red[8 + e] / (float)Nv);
    bl *= (float)Ev;
    outAux[0] = 0.01f * bl + 0.001f * (red[16] / (float)Nv);
  }
  __syncthreads();
  for (int e = 0; e < 8; ++e) h[e] = hist[t][e];
  for (int j = 0; j < 32; ++j) {
    int i = base + j; int e = tgt[i]; int r = h[e]++;
    int kp = (r < CAPv) ? 1 : 0;
    keep[i] = kp;
    if (kp) dstNK[e * CAPv + r] = i;
  }
}

// ---------------- pack tokens -> fp8 ----------------
__global__ __launch_bounds__(256) void pack8_kernel(const float* __restrict__ x,
    const int* __restrict__ dstNK, u8* __restrict__ buf)
{
  int s = blockIdx.x * 4 + (threadIdx.x >> 6);
  int ln = threadIdx.x & 63;
  int i = dstNK[s];
  u8* dst = buf + (size_t)s * Dv;
  if (i >= 0) {
    const float* src = x + (size_t)(i >> 1) * Dv;
    #pragma unroll
    for (int j = 0; j < 4; ++j) {
      int d0 = ln * 16 + j * 4;
      float4 v = *(const float4*)(src + d0);
      *(unsigned*)(dst + d0) = pack4(v, 1.f);
    }
  } else {
    #pragma unroll
    for (int j = 0; j < 4; ++j) *(unsigned*)(dst + ln * 16 + j * 4) = 0u;
  }
}

// ------- batched weight conversion: 128x256 tiles, 1KB reads / 128B writes -------
#define NSEG 9
struct WTab {
  const float* in[NSEG];
  u8* out[NSEG];
  int R[NSEG], C[NSEG], ldo[NSEG], nxy[NSEG], nx[NSEG];
  int start[NSEG];
};

__global__ __launch_bounds__(256) void wprep_kernel(WTab T) {
  __shared__ u8 tile[128][264];
  int b = blockIdx.x;
  int s = 0;
  #pragma unroll
  for (int i = 1; i < NSEG; ++i) if (b >= T.start[i]) s = i;
  int rb = b - T.start[s];
  const float* in = T.in[s];
  u8* out = T.out[s];
  int t = threadIdx.x;
  if (T.nx[s] == 0) {
    int i = rb * 256 + t;
    float4 v = *(const float4*)(in + (size_t)i * 4);
    *(unsigned*)(out + (size_t)i * 4) = pack4(v, 16.f);
    return;
  }
  int R = T.R[s], C = T.C[s], ldo = T.ldo[s];
  int z = rb / T.nxy[s], r2 = rb % T.nxy[s];
  int by = r2 / T.nx[s], bx = r2 % T.nx[s];
  in += (size_t)z * R * C;
  out += (size_t)z * (size_t)R * C;   // z>0 only when ldo==R (batched experts)
  int r0 = by * 128, c0 = bx * 256;
  int rr = t >> 5;           // 0..7
  int cc8 = (t & 31) * 8;    // 0..248, 1KB/row across 32 threads
  #pragma unroll
  for (int p = 0; p < 16; ++p) {
    int r = rr + p * 8;
    const float* rp = in + (size_t)(r0 + r) * C + c0 + cc8;
    float4 v0 = *(const float4*)(rp);
    float4 v1 = *(const float4*)(rp + 4);
    *(unsigned*)(&tile[r][cc8])     = pack4(v0, 16.f);
    *(unsigned*)(&tile[r][cc8 + 4]) = pack4(v1, 16.f);
  }
  __syncthreads();
  int c = t;                 // 0..255: one full 128B column per thread
  u8* op = out + (size_t)(c0 + c) * ldo + r0;
  #pragma unroll
  for (int q8 = 0; q8 < 8; ++q8) {
    u32x4 w;
    #pragma unroll
    for (int j = 0; j < 4; ++j) {
      int r = q8 * 16 + j * 4;
      w[j] = (unsigned)tile[r][c] | ((unsigned)tile[r+1][c] << 8)
           | ((unsigned)tile[r+2][c] << 16) | ((unsigned)tile[r+3][c] << 24);
    }
    *(u32x4*)(op + q8 * 16) = w;
  }
}

// ===== 128x128 4-wave MX-fp8 GEMM, BK=128, single-buffer =====
// MODE 1: SwiGLU->fp8 (cnt exit)  2: scatter fp8 (cnt exit)  4: fp8 out
// MODE 5: gelu->fp8 (split-K A)   6: f32 out                 7: fp8 out x16
template<int MODE>
__global__ __launch_bounds__(256, 3) void gemm128f8(
    const u8* __restrict__ A, const u8* __restrict__ A2, int splitK,
    const u8* __restrict__ B, void* __restrict__ C,
    const int* __restrict__ dst, const int* __restrict__ cnt,
    int Ksz, int lda, int ldb, int ldc, int ntm,
    size_t sA, size_t sB, size_t sC, unsigned sclA, unsigned sclB)
{
  __shared__ char smem[32768];
  int e = blockIdx.y;
  int nwgx = gridDim.x, bid0 = blockIdx.x;
  int q = nwgx >> 3, r = nwgx & 7;
  int xcd = bid0 & 7, lo2 = bid0 >> 3;
  int bid = (xcd < r ? xcd * (q + 1) : r * (q + 1) + (xcd - r) * q) + lo2;
  int tm = bid % ntm, tn = bid / ntm;
  if (MODE == 1 || MODE == 2) {
    if (tm * 128 >= cnt[e]) return;
  }
  const u8* Ae = A + (size_t)e * sA;
  const u8* Be = B + (size_t)e * sB;
  long long bdelta = (const char*)A2 - (const char*)Ae;
  int tid = threadIdx.x, wv = tid >> 6, ln = tid & 63;
  int lnl = ln & 15, lnh = ln >> 4;

  const u8* aP[4]; const u8* bP[4];
  unsigned aL[4], bL[4];
  #pragma unroll
  for (int i = 0; i < 4; ++i) {
    int row = i * 32 + wv * 8 + (ln >> 3);
    int c = (ln & 7) ^ (row & 7);
    int cp = ((c & 3) << 1) | (c >> 2);
    aP[i] = Ae + (size_t)(tm * 128 + row) * lda + cp * 16;
    int brow;
    if (MODE == 1) {
      brow = (row < 64) ? (tn * 64 + row) : (Hv + tn * 64 + (row - 64));
    } else {
      brow = tn * 128 + row;
    }
    bP[i] = Be + (size_t)brow * ldb + cp * 16;
    aL[i] = i * 4096 + wv * 1024;
    bL[i] = 16384 + i * 4096 + wv * 1024;
  }

  int arow0 = wv * 32 + lnl;
  int ksw0 = (lnh << 4);
  int ksw1 = 64 + (lnh << 4);

  f32x4 acc[2][8];
  #pragma unroll
  for (int m = 0; m < 2; ++m)
    #pragma unroll
    for (int n = 0; n < 8; ++n) acc[m][n] = (f32x4){0.f, 0.f, 0.f, 0.f};

  for (int k0 = 0; k0 < Ksz; k0 += 128) {
    long long kbA;
    if (MODE == 5 && k0 >= splitK) kbA = bdelta + (long long)(k0 - splitK);
    else kbA = (long long)k0;
    #pragma unroll
    for (int i = 0; i < 4; ++i) gload16(aP[i] + kbA, smem + aL[i]);
    #pragma unroll
    for (int i = 0; i < 4; ++i) gload16(bP[i] + (size_t)k0, smem + bL[i]);
    __syncthreads();

    i32x8 af[2];
    #pragma unroll
    for (int mi = 0; mi < 2; ++mi) {
      int row = arow0 + mi * 16;
      int swz = (row & 7) << 4;
      *(i32x4*)&af[mi] = *(const i32x4*)(smem + row * 128 + (ksw0 ^ swz));
      *((i32x4*)&af[mi] + 1) = *(const i32x4*)(smem + row * 128 + (ksw1 ^ swz));
    }
    #pragma unroll
    for (int n = 0; n < 8; ++n) {
      int row = n * 16 + lnl;
      int swz = (row & 7) << 4;
      i32x8 bf;
      *(i32x4*)&bf = *(const i32x4*)(smem + 16384 + row * 128 + (ksw0 ^ swz));
      *((i32x4*)&bf + 1) = *(const i32x4*)(smem + 16384 + row * 128 + (ksw1 ^ swz));
      acc[0][n] = __builtin_amdgcn_mfma_scale_f32_16x16x128_f8f6f4(
          af[0], bf, acc[0][n], 0, 0, 0, sclA, 0, sclB);
      acc[1][n] = __builtin_amdgcn_mfma_scale_f32_16x16x128_f8f6f4(
          af[1], bf, acc[1][n], 0, 0, 0, sclA, 0, sclB);
    }
    __syncthreads();
  }

  int rbase = tm * 128 + wv * 32 + (lnh << 2);
  if (MODE == 1) {
    u8* Cp = (u8*)C + (size_t)e * sC;
    #pragma unroll
    for (int mi = 0; mi < 2; ++mi)
      #pragma unroll
      for (int n = 0; n < 4; ++n) {
        int col = tn * 64 + n * 16 + lnl;
        #pragma unroll
        for (int v = 0; v < 4; ++v) {
          float g = acc[mi][n][v];
          float u = acc[mi][n + 4][v];
          float sg = g / (1.f + __expf(-g));
          Cp[(size_t)(rbase + mi * 16 + v) * ldc + col] = f2e4h(sg * u);
        }
      }
  } else if (MODE == 2) {
    u8* Cq = (u8*)C;
    #pragma unroll
    for (int mi = 0; mi < 2; ++mi)
      #pragma unroll
      for (int v = 0; v < 4; ++v) {
        int gr = rbase + mi * 16 + v;
        int i = dst[e * CAPv + gr];
        if (i >= 0) {
          #pragma unroll
          for (int n = 0; n < 8; ++n) {
            int col = tn * 128 + n * 16 + lnl;
            Cq[(size_t)i * Dv + col] = f2e4h(acc[mi][n][v]);
          }
        }
      }
  } else if (MODE == 4) {
    u8* Cp = (u8*)C;
    #pragma unroll
    for (int mi = 0; mi < 2; ++mi)
      #pragma unroll
      for (int n = 0; n < 8; ++n) {
        int col = tn * 128 + n * 16 + lnl;
        #pragma unroll
        for (int v = 0; v < 4; ++v)
          Cp[(size_t)(rbase + mi * 16 + v) * ldc + col] = f2e4h(acc[mi][n][v]);
      }
  } else if (MODE == 5) {
    u8* Cp = (u8*)C;
    #pragma unroll
    for (int mi = 0; mi < 2; ++mi)
      #pragma unroll
      for (int n = 0; n < 8; ++n) {
        int col = tn * 128 + n * 16 + lnl;
        #pragma unroll
        for (int v = 0; v < 4; ++v) {
          float xg = acc[mi][n][v];
          float gl = 0.5f * xg * (1.f + erff(xg * 0.70710678118654752f));
          Cp[(size_t)(rbase + mi * 16 + v) * ldc + col] = f2e4h(gl);
        }
      }
  } else if (MODE == 7) {
    u8* Cp = (u8*)C;
    #pragma unroll
    for (int mi = 0; mi < 2; ++mi)
      #pragma unroll
      for (int n = 0; n < 8; ++n) {
        int col = tn * 128 + n * 16 + lnl;
        #pragma unroll
        for (int v = 0; v < 4; ++v)
          Cp[(size_t)(rbase + mi * 16 + v) * ldc + col] = f2e4h(acc[mi][n][v] * 16.f);
      }
  } else {
    float* Cp = (float*)C;
    #pragma unroll
    for (int mi = 0; mi < 2; ++mi)
      #pragma unroll
      for (int n = 0; n < 8; ++n) {
        int col = tn * 128 + n * 16 + lnl;
        #pragma unroll
        for (int v = 0; v < 4; ++v)
          Cp[(size_t)(rbase + mi * 16 + v) * ldc + col] = acc[mi][n][v];
      }
  }
}

// ---------------- scores + masked softmax + Cmsg ----------------
__global__ __launch_bounds__(256) void scores8_kernel(
    const u8* __restrict__ MQ, const u8* __restrict__ SEL8,
    const int* __restrict__ keep, u8* __restrict__ Cmsg)
{
  int wv = threadIdx.x >> 6, ln = threadIdx.x & 63;
  int n = blockIdx.x * 4 + wv;
  const u8* m0 = MQ + (size_t)(2 * n) * 2048;
  const u8* m1 = MQ + (size_t)(2 * n + 1) * 2048;
  const u8* t0 = m0 + 1024;
  const u8* t1 = m1 + 1024;
  const u8* s0p = SEL8 + (size_t)(2 * n) * 1024;
  const u8* s1p = SEL8 + (size_t)(2 * n + 1) * 1024;
  int d0 = ln * 16;
  float a0[16], a1[16], b0[16], b1[16];
  dec16(t0 + d0, a0); dec16(t1 + d0, a1);
  dec16(s0p + d0, b0); dec16(s1p + d0, b1);
  float s00 = 0, s01 = 0, s10 = 0, s11 = 0;
  #pragma unroll
  for (int t = 0; t < 16; ++t) {
    s00 += a0[t] * b0[t]; s01 += a0[t] * b1[t];
    s10 += a1[t] * b0[t]; s11 += a1[t] * b1[t];
  }
  #pragma unroll
  for (int off = 32; off >= 1; off >>= 1) {
    s00 += __shfl_xor(s00, off, 64);
    s01 += __shfl_xor(s01, off, 64);
    s10 += __shfl_xor(s10, off, 64);
    s11 += __shfl_xor(s11, off, 64);
  }
  const float inv = 0.03125f;
  int kp0 = keep[2 * n], kp1 = keep[2 * n + 1];
  float A00, A01, A10, A11;
  {
    float v0 = kp0 ? s00 * inv : -1e9f;
    float v1 = (kp0 && kp1) ? s01 * inv : -1e9f;
    float mx = fmaxf(v0, v1);
    float e0 = expf(v0 - mx), e1 = expf(v1 - mx);
    float den = e0 + e1;
    float a0v = kp0 ? e0 / den : 0.f;
    float a1v = (kp0 && kp1) ? e1 / den : 0.f;
    float s = fmaxf(a0v + a1v, 1e-12f);
    A00 = a0v / s; A01 = a1v / s;
  }
  {
    float v0 = (kp1 && kp0) ? s10 * inv : -1e9f;
    float v1 = kp1 ? s11 * inv : -1e9f;
    float mx = fmaxf(v0, v1);
    float e0 = expf(v0 - mx), e1 = expf(v1 - mx);
    float den = e0 + e1;
    float a0v = (kp1 && kp0) ? e0 / den : 0.f;
    float a1v = kp1 ? e1 / den : 0.f;
    float s = fmaxf(a0v + a1v, 1e-12f);
    A10 = a0v / s; A11 = a1v / s;
  }
  float f0[16], f1[16];
  dec16(m0 + d0, f0); dec16(m1 + d0, f1);
  u8* c0 = Cmsg + (size_t)(2 * n) * 1024 + d0;
  u8* c1 = Cmsg + (size_t)(2 * n + 1) * 1024 + d0;
  #pragma unroll
  for (int j = 0; j < 4; ++j) {
    int t = j * 4;
    *(unsigned*)(c0 + j * 4) = cvtpk4(
        A00 * f0[t] + A01 * f1[t],     A00 * f0[t+1] + A01 * f1[t+1],
        A00 * f0[t+2] + A01 * f1[t+2], A00 * f0[t+3] + A01 * f1[t+3]);
    *(unsigned*)(c1 + j * 4) = cvtpk4(
        A10 * f0[t] + A11 * f1[t],     A10 * f0[t+1] + A11 * f1[t+1],
        A10 * f0[t+2] + A11 * f1[t+2], A10 * f0[t+3] + A11 * f1[t+3]);
  }
}

// ---------------- combine2: FCAT = [sum w_k sel_k | sum w_k gelu_k] fp8 ----------------
__global__ __launch_bounds__(256) void combine2_kernel(
    const u8* __restrict__ sel8, const u8* __restrict__ g8,
    const int* __restrict__ keep, const float* __restrict__ tkprob,
    u8* __restrict__ fcat)
{
  int n = blockIdx.x;
  int t = threadIdx.x;
  float kp0 = keep[2 * n] ? 1.f : 0.f, kp1 = keep[2 * n + 1] ? 1.f : 0.f;
  float p0 = tkprob[2 * n] * kp0, p1 = tkprob[2 * n + 1] * kp1;
  float s = fmaxf(p0 + p1, 1e-12f);
  float w0 = p0 / s, w1 = p1 / s;
  unsigned a = *(const unsigned*)(sel8 + (size_t)(2 * n) * 1024 + t * 4);
  unsigned b = *(const unsigned*)(sel8 + (size_t)(2 * n + 1) * 1024 + t * 4);
  float fa[4], fb[4];
  dec4(a, fa); dec4(b, fb);
  *(unsigned*)(fcat + (size_t)n * 3072 + t * 4) = cvtpk4(
      w0 * fa[0] + w1 * fb[0], w0 * fa[1] + w1 * fb[1],
      w0 * fa[2] + w1 * fb[2], w0 * fa[3] + w1 * fb[3]);
  const u8* ga = g8 + (size_t)(2 * n) * 2048 + t * 8;
  const u8* gb = g8 + (size_t)(2 * n + 1) * 2048 + t * 8;
  #pragma unroll
  for (int h = 0; h < 2; ++h) {
    unsigned xa = *(const unsigned*)(ga + h * 4);
    unsigned xb = *(const unsigned*)(gb + h * 4);
    dec4(xa, fa); dec4(xb, fb);
    *(unsigned*)(fcat + (size_t)n * 3072 + 1024 + t * 8 + h * 4) = cvtpk4(
        w0 * fa[0] + w1 * fb[0], w0 * fa[1] + w1 * fb[1],
        w0 * fa[2] + w1 * fb[2], w0 * fa[3] + w1 * fb[3]);
  }
}

extern "C" void kernel_launch(void* const* d_in, const int* in_sizes, int n_in,
                              void* d_out, int out_size, void* d_ws, size_t ws_size,
                              hipStream_t stream) {
  const float* x      = (const float*)d_in[0];
  const float* gate_w = (const float*)d_in[1];
  const float* w13    = (const float*)d_in[2];
  const float* w2     = (const float*)d_in[3];
  const float* msg_w  = (const float*)d_in[4];
  const float* q_w    = (const float*)d_in[5];
  const float* k_w    = (const float*)d_in[6];
  const float* upd_w1 = (const float*)d_in[7];
  const float* upd_w2 = (const float*)d_in[8];
  const float* o_w    = (const float*)d_in[9];
  float* out = (float*)d_out;
  float* outAux = out + (size_t)Nv * Dv;
  float* outIdx = outAux + 1;

  char* ws = (char*)d_ws;
  const size_t MBc = 1ull << 20;
  int*   tkidx  = (int*)(ws + 0);
  float* tkprob = (float*)(ws + 32768);
  int*   keepA  = (int*)(ws + 65536);
  int*   dstNK  = (int*)(ws + 98304);
  float* red    = (float*)(ws + 143360);
  int*   cntA   = (int*)(ws + 147456);
  u8*  BUF8  = (u8*)(ws + 1 * MBc);
  u8*  ACT8  = (u8*)(ws + 12 * MBc);
  u8*  W13B8 = (u8*)(ws + 41 * MBc);
  u8*  M8s   = (u8*)(ws + 85 * MBc);
  u8*  Q8s   = (u8*)(ws + 86 * MBc);
  u8*  K8T   = (u8*)(ws + 87 * MBc);
  u8*  W2B8r = (u8*)(ws + 88 * MBc);
  u8*  U28s  = (u8*)(ws + 110 * MBc);
  u8*  MTB8  = (u8*)(ws + 112 * MBc);
  u8*  WCAT8 = (u8*)(ws + 114 * MBc);
  u8*  P38   = (u8*)(ws + 117 * MBc);
  u8*  SEL8  = (u8*)(ws + 136 * MBc);
  u8*  UPD1B8= (u8*)(ws + 149 * MBc);
  u8*  FCAT8 = (u8*)(ws + 160 * MBc);
  u8*  MQ8   = (u8*)(ws + 1 * MBc);
  u8*  CMSG8 = (u8*)(ws + 18 * MBc);
  u8*  G1B8  = (u8*)(ws + 27 * MBc);

  hipMemsetAsync(red, 0, 68, stream);
  hipMemsetAsync(dstNK, 0xFF, Ev * CAPv * 4, stream);
  hipMemsetAsync(SEL8, 0, (size_t)NKv * Dv, stream);

  router_kernel<<<Nv / 4, 256, 0, stream>>>(x, gate_w, tkidx, tkprob, red, outIdx);
  rank_kernel<<<1, 256, 0, stream>>>(tkidx, keepA, dstNK, cntA, red, outAux);
  pack8_kernel<<<(Ev * CAPv) / 4, 256, 0, stream>>>(x, dstNK, BUF8);

  WTab T;
  T.in[0]=w13;    T.out[0]=W13B8; T.R[0]=Dv;   T.C[0]=TH2v; T.ldo[0]=Dv;   T.nxy[0]=176; T.nx[0]=22;
  T.in[1]=w2;     T.out[1]=W2B8r; T.R[1]=Hv;   T.C[1]=Dv;   T.ldo[1]=Hv;   T.nxy[1]=88;  T.nx[1]=4;
  T.in[2]=upd_w1; T.out[2]=UPD1B8;T.R[2]=2048; T.C[2]=2048; T.ldo[2]=2048; T.nxy[2]=128; T.nx[2]=8;
  T.in[3]=msg_w;  T.out[3]=MTB8;  T.R[3]=Dv;   T.C[3]=Dv;   T.ldo[3]=Dv;   T.nxy[3]=32;  T.nx[3]=4;
  T.in[4]=o_w;    T.out[4]=WCAT8; T.R[4]=Dv;   T.C[4]=Dv;   T.ldo[4]=3072; T.nxy[4]=32;  T.nx[4]=4;
  T.in[5]=k_w;    T.out[5]=K8T;   T.R[5]=Dv;   T.C[5]=Dv;   T.ldo[5]=Dv;   T.nxy[5]=32;  T.nx[5]=4;
  T.in[6]=msg_w;  T.out[6]=M8s;   T.nx[6]=0; T.R[6]=0; T.C[6]=0; T.ldo[6]=0; T.nxy[6]=0;
  T.in[7]=q_w;    T.out[7]=Q8s;   T.nx[7]=0; T.R[7]=0; T.C[7]=0; T.ldo[7]=0; T.nxy[7]=0;
  T.in[8]=upd_w2; T.out[8]=U28s;  T.nx[8]=0; T.R[8]=0; T.C[8]=0; T.ldo[8]=0; T.nxy[8]=0;
  T.start[0]=0; T.start[1]=1408; T.start[2]=2112; T.start[3]=2240;
  T.start[4]=2272; T.start[5]=2304; T.start[6]=2336; T.start[7]=3360; T.start[8]=4384;
  wprep_kernel<<<6432, 256, 0, stream>>>(T);

  // G1: MX-fp8 SwiGLU -> ACT8 (early-exit via cntA)
  gemm128f8<1><<<dim3((CAPv / 128) * (Hv / 64), Ev), 256, 0, stream>>>(
      BUF8, BUF8, 1 << 30, W13B8, (void*)ACT8, nullptr, cntA,
      Dv, Dv, Dv, Hv, CAPv / 128,
      (size_t)CAPv * Dv, (size_t)TH2v * Dv, (size_t)CAPv * Hv, 0x7F7F7F7Fu, 0x7B7B7B7Bu);

  // W_s^T = (msg@k) @ q^T  (MODE 7: fp8 x16 out, no conversion round-trips)
  gemm128f8<7><<<dim3(64, 1), 256, 0, stream>>>(
      M8s, M8s, 1 << 30, K8T, (void*)P38, nullptr, nullptr,
      Dv, Dv, Dv, Dv, 8, 0, 0, 0, 0x7B7B7B7Bu, 0x7B7B7B7Bu);
  gemm128f8<7><<<dim3(64, 1), 256, 0, stream>>>(
      P38, P38, 1 << 30, Q8s, (void*)(MTB8 + (size_t)Dv * Dv), nullptr, nullptr,
      Dv, Dv, Dv, Dv, 8, 0, 0, 0, 0x7B7B7B7Bu, 0x7B7B7B7Bu);
  // T2^T = o_w^T @ upd_w2^T -> WCAT8+1024 (ldc 3072)
  gemm128f8<7><<<dim3(128, 1), 256, 0, stream>>>(
      WCAT8, WCAT8, 1 << 30, U28s, (void*)(WCAT8 + 1024), nullptr, nullptr,
      Dv, 3072, Dv, 3072, 8, 0, 0, 0, 0x7B7B7B7Bu, 0x7B7B7B7Bu);

  // G2: MX-fp8 GEMM + scatter -> SEL8 (early-exit via cntA)
  gemm128f8<2><<<dim3((CAPv / 128) * (Dv / 128), Ev), 256, 0, stream>>>(
      ACT8, ACT8, 1 << 30, W2B8r, (void*)SEL8, dstNK, cntA,
      Hv, Hv, Hv, Dv, CAPv / 128,
      (size_t)CAPv * Hv, (size_t)Dv * Hv, 0, 0x7F7F7F7Fu, 0x7B7B7B7Bu);

  // collaboration: fused [M|T] GEMM, then scores
  gemm128f8<4><<<dim3(64 * 16, 1), 256, 0, stream>>>(
      SEL8, SEL8, 1 << 30, MTB8, (void*)MQ8, nullptr, nullptr,
      Dv, Dv, Dv, 2048, 64, 0, 0, 0, 0x7F7F7F7Fu, 0x7B7B7B7Bu);
  scores8_kernel<<<Nv / 4, 256, 0, stream>>>(MQ8, SEL8, keepA, CMSG8);

  // update MLP: gelu([SEL8|CMSG8] @ upd_w1) -> G1B8
  gemm128f8<5><<<dim3(64 * 16, 1), 256, 0, stream>>>(
      SEL8, CMSG8, Dv, UPD1B8, (void*)G1B8, nullptr, nullptr,
      2048, Dv, 2048, 2048, 64, 0, 0, 0, 0x7F7F7F7Fu, 0x7B7B7B7Bu);

  // FCAT = [sum w sel | sum w gelu], final fused GEMM -> out (f32)
  combine2_kernel<<<Nv, 256, 0, stream>>>(SEL8, G1B8, keepA, tkprob, FCAT8);
  gemm128f8<6><<<dim3(32 * 8, 1), 256, 0, stream>>>(
      FCAT8, FCAT8, 1 << 30, WCAT8, (void*)out, nullptr, nullptr,
      3072, 3072, 3072, Dv, 32, 0, 0, 0, 0x7F7F7F7Fu, 0x7B7B7B7Bu);

  (void)in_sizes; (void)n_in; (void)out_size; (void)ws_size;
}

// Round 17
// 405.060 us; speedup vs baseline: 1.0147x; 1.0147x over previous
//
#include <hip/hip_runtime.h>
#include <math.h>

#define Dv 1024
#define Ev 8
#define Hv 2816
#define Nv 4096
#define NKv 8192
#define CAPv 1280
#define TH2v 5632

typedef unsigned short u16;
typedef unsigned char u8;
typedef __attribute__((ext_vector_type(4))) float f32x4;
typedef __attribute__((ext_vector_type(4))) int i32x4;
typedef __attribute__((ext_vector_type(8))) int i32x8;
typedef __attribute__((ext_vector_type(4))) unsigned u32x4;

typedef const __attribute__((address_space(1))) void* as1_cvp;
typedef __attribute__((address_space(3))) void* as3_vp;

// f32 -> OCP e4m3fn, RNE, saturate to 448 (software fallback)
__device__ __forceinline__ unsigned f2e4(float f) {
  unsigned u = __float_as_uint(f);
  unsigned sgn = (u >> 24) & 0x80u;
  unsigned ax = u & 0x7FFFFFFFu;
  if (ax >= 0x43E00000u) return sgn | 0x7Eu;
  if (ax < 0x3C800000u) {
    int qv = (int)rintf(__uint_as_float(ax) * 512.f);
    return sgn | (unsigned)qv;
  }
  unsigned lsb = (ax >> 20) & 1u;
  unsigned rr = ax + 0x0007FFFFu + lsb;
  unsigned ee = rr >> 23;
  unsigned mm = (rr >> 20) & 7u;
  if (ee > 135u) return sgn | 0x7Eu;
  return sgn | ((ee - 120u) << 3) | mm;
}
// e4m3fn -> f32 (software fallback)
__device__ __forceinline__ float e42f(unsigned v) {
  unsigned s = (v & 0x80u) << 24, e = (v >> 3) & 15u, m = v & 7u;
  if (e) return __uint_as_float(s | ((e + 120u) << 23) | (m << 20));
  return __uint_as_float(__float_as_uint((float)m * 0.001953125f) | s);
}

// packed converters (HW when available)
__device__ __forceinline__ unsigned cvtpk4(float a, float b, float c, float d) {
#if __has_builtin(__builtin_amdgcn_cvt_pk_fp8_f32)
  int w = __builtin_amdgcn_cvt_pk_fp8_f32(a, b, 0, false);
  w = __builtin_amdgcn_cvt_pk_fp8_f32(c, d, w, true);
  return (unsigned)w;
#else
  return f2e4(a) | (f2e4(b) << 8) | (f2e4(c) << 16) | (f2e4(d) << 24);
#endif
}
__device__ __forceinline__ u8 f2e4h(float a) {
#if __has_builtin(__builtin_amdgcn_cvt_pk_fp8_f32)
  return (u8)(__builtin_amdgcn_cvt_pk_fp8_f32(a, a, 0, false) & 0xffu);
#else
  return (u8)f2e4(a);
#endif
}
__device__ __forceinline__ void dec16(const u8* p, float* o) {
  const unsigned* w = (const unsigned*)p;
#if __has_builtin(__builtin_amdgcn_cvt_pk_f32_fp8)
  #pragma unroll
  for (int j = 0; j < 4; ++j) {
    int x = (int)w[j];
    auto lo = __builtin_amdgcn_cvt_pk_f32_fp8(x, false);
    auto hi = __builtin_amdgcn_cvt_pk_f32_fp8(x, true);
    o[j*4+0] = lo[0]; o[j*4+1] = lo[1]; o[j*4+2] = hi[0]; o[j*4+3] = hi[1];
  }
#else
  #pragma unroll
  for (int j = 0; j < 4; ++j) {
    unsigned x = w[j];
    o[j*4+0] = e42f(x & 255u);
    o[j*4+1] = e42f((x >> 8) & 255u);
    o[j*4+2] = e42f((x >> 16) & 255u);
    o[j*4+3] = e42f((x >> 24) & 255u);
  }
#endif
}
__device__ __forceinline__ void dec4(unsigned x, float* o) {
#if __has_builtin(__builtin_amdgcn_cvt_pk_f32_fp8)
  auto lo = __builtin_amdgcn_cvt_pk_f32_fp8((int)x, false);
  auto hi = __builtin_amdgcn_cvt_pk_f32_fp8((int)x, true);
  o[0] = lo[0]; o[1] = lo[1]; o[2] = hi[0]; o[3] = hi[1];
#else
  o[0] = e42f(x & 255u); o[1] = e42f((x >> 8) & 255u);
  o[2] = e42f((x >> 16) & 255u); o[3] = e42f((x >> 24) & 255u);
#endif
}
__device__ __forceinline__ unsigned pack4(float4 v, float s) {
  return cvtpk4(v.x * s, v.y * s, v.z * s, v.w * s);
}
__device__ __forceinline__ void gload16(const void* g, void* l) {
  __builtin_amdgcn_global_load_lds((as1_cvp)g, (as3_vp)l, 16, 0, 0);
}

// ---------------- router ----------------
__global__ __launch_bounds__(256) void router_kernel(
    const float* __restrict__ x, const float* __restrict__ gw,
    int* __restrict__ tkidx, float* __restrict__ tkprob,
    float* __restrict__ red, float* __restrict__ outIdx)
{
  __shared__ float lred[17];
  int tid = threadIdx.x;
  if (tid < 17) lred[tid] = 0.f;
  __syncthreads();
  int wv = tid >> 6, ln = tid & 63;
  int n = blockIdx.x * 4 + wv;
  float a[8] = {0.f,0.f,0.f,0.f,0.f,0.f,0.f,0.f};
  const float* xr = x + (size_t)n * Dv;
  #pragma unroll
  for (int it = 0; it < 16; ++it) {
    int d = ln + it * 64;
    float xs = xr[d];
    float4 g0 = *(const float4*)(gw + (size_t)d * 8);
    float4 g1 = *(const float4*)(gw + (size_t)d * 8 + 4);
    a[0] += xs * g0.x; a[1] += xs * g0.y; a[2] += xs * g0.z; a[3] += xs * g0.w;
    a[4] += xs * g1.x; a[5] += xs * g1.y; a[6] += xs * g1.z; a[7] += xs * g1.w;
  }
  #pragma unroll
  for (int off = 32; off >= 1; off >>= 1) {
    #pragma unroll
    for (int e = 0; e < 8; ++e) a[e] += __shfl_xor(a[e], off, 64);
  }
  int i1 = 0; float v1 = a[0];
  #pragma unroll
  for (int e = 1; e < 8; ++e) if (a[e] > v1) { v1 = a[e]; i1 = e; }
  int i2 = -1; float v2 = -1e30f;
  #pragma unroll
  for (int e = 0; e < 8; ++e) if (e != i1 && a[e] > v2) { v2 = a[e]; i2 = e; }
  float Z = 0.f;
  #pragma unroll
  for (int e = 0; e < 8; ++e) Z += expf(a[e] - v1);
  float zlse = v1 + logf(Z);
  float t = expf(v2 - v1);
  float p1 = 1.f / (1.f + t);
  float p2 = t * p1;
  if (ln == 0) {
    tkidx[2*n] = i1; tkidx[2*n+1] = i2;
    tkprob[2*n] = p1; tkprob[2*n+1] = p2;
    outIdx[2*n] = (float)i1; outIdx[2*n+1] = (float)i2;
    #pragma unroll
    for (int e = 0; e < 8; ++e) atomicAdd(&lred[e], expf(a[e] - v1) / Z);
    atomicAdd(&lred[8 + i1], 1.f);
    atomicAdd(&lred[16], zlse * zlse);
  }
  __syncthreads();
  if (tid < 17) atomicAdd(&red[tid], lred[tid]);
}

// ---------------- exact stable rank + counts + aux ----------------
__global__ __launch_bounds__(256) void rank_kernel(const int* __restrict__ tgt,
    int* __restrict__ keep, int* __restrict__ dstNK, int* __restrict__ cnt,
    const float* __restrict__ red, float* __restrict__ outAux)
{
  __shared__ int hist[256][8];
  int t = threadIdx.x;
  int h[8] = {0,0,0,0,0,0,0,0};
  int base = t * 32;
  for (int j = 0; j < 32; ++j) h[tgt[base + j]]++;
  for (int e = 0; e < 8; ++e) hist[t][e] = h[e];
  __syncthreads();
  if (t < 8) {
    int run = 0;
    for (int tt = 0; tt < 256; ++tt) { int v = hist[tt][t]; hist[tt][t] = run; run += v; }
    cnt[t] = run < CAPv ? run : CAPv;
  }
  if (t == 0) {
    float bl = 0.f;
    for (int e = 0; e < 8; ++e) bl += (red[e] / (float)Nv) * (red[8 + e] / (float)Nv);
    bl *= (float)Ev;
    outAux[0] = 0.01f * bl + 0.001f * (red[16] / (float)Nv);
  }
  __syncthreads();
  for (int e = 0; e < 8; ++e) h[e] = hist[t][e];
  for (int j = 0; j < 32; ++j) {
    int i = base + j; int e = tgt[i]; int r = h[e]++;
    int kp = (r < CAPv) ? 1 : 0;
    keep[i] = kp;
    if (kp) dstNK[e * CAPv + r] = i;
  }
}

// ---------------- pack tokens -> fp8 ----------------
__global__ __launch_bounds__(256) void pack8_kernel(const float* __restrict__ x,
    const int* __restrict__ dstNK, u8* __restrict__ buf)
{
  int s = blockIdx.x * 4 + (threadIdx.x >> 6);
  int ln = threadIdx.x & 63;
  int i = dstNK[s];
  u8* dst = buf + (size_t)s * Dv;
  if (i >= 0) {
    const float* src = x + (size_t)(i >> 1) * Dv;
    #pragma unroll
    for (int j = 0; j < 4; ++j) {
      int d0 = ln * 16 + j * 4;
      float4 v = *(const float4*)(src + d0);
      *(unsigned*)(dst + d0) = pack4(v, 1.f);
    }
  } else {
    #pragma unroll
    for (int j = 0; j < 4; ++j) *(unsigned*)(dst + ln * 16 + j * 4) = 0u;
  }
}

// ------- batched weight conversion: 128x128 tiles, 512B reads / 128B writes -------
#define NSEG 9
struct WTab {
  const float* in[NSEG];
  u8* out[NSEG];
  int R[NSEG], C[NSEG], ldo[NSEG], nxy[NSEG], nx[NSEG];
  int start[NSEG];
};

__global__ __launch_bounds__(256) void wprep_kernel(WTab T) {
  __shared__ u8 tile[128][132];
  int b = blockIdx.x;
  int s = 0;
  #pragma unroll
  for (int i = 1; i < NSEG; ++i) if (b >= T.start[i]) s = i;
  int rb = b - T.start[s];
  const float* in = T.in[s];
  u8* out = T.out[s];
  int t = threadIdx.x;
  if (T.nx[s] == 0) {
    int i = rb * 256 + t;
    float4 v = *(const float4*)(in + (size_t)i * 4);
    *(unsigned*)(out + (size_t)i * 4) = pack4(v, 16.f);
    return;
  }
  int R = T.R[s], C = T.C[s], ldo = T.ldo[s];
  int z = rb / T.nxy[s], r2 = rb % T.nxy[s];
  int by = r2 / T.nx[s], bx = r2 % T.nx[s];
  in += (size_t)z * R * C;
  out += (size_t)z * (size_t)R * C;   // z>0 only when ldo==R (batched experts)
  int r0 = by * 128, c0 = bx * 128;
  int rr = t >> 5;           // 0..7
  int cc4 = (t & 31) * 4;    // 0..124, 512B/row across 32 threads
  #pragma unroll
  for (int p = 0; p < 16; ++p) {
    int r = rr + p * 8;
    float4 v = *(const float4*)(in + (size_t)(r0 + r) * C + c0 + cc4);
    *(unsigned*)(&tile[r][cc4]) = pack4(v, 16.f);   // convert on load side
  }
  __syncthreads();
  int c = t >> 1;            // 0..127
  int rh = (t & 1) * 64;     // 0 or 64: 2 threads cover a 128B column chunk
  u8* op = out + (size_t)(c0 + c) * ldo + r0 + rh;
  #pragma unroll
  for (int q8 = 0; q8 < 4; ++q8) {
    u32x4 w;
    #pragma unroll
    for (int j = 0; j < 4; ++j) {
      int r = rh + q8 * 16 + j * 4;
      w[j] = (unsigned)tile[r][c] | ((unsigned)tile[r+1][c] << 8)
           | ((unsigned)tile[r+2][c] << 16) | ((unsigned)tile[r+3][c] << 24);
    }
    *(u32x4*)(op + q8 * 16) = w;
  }
}

// ===== 128x128 4-wave MX-fp8 GEMM, BK=128, single-buffer =====
// MODE 1: SwiGLU->fp8 (cnt exit)  2: scatter fp8 (cnt exit)  4: fp8 out
// MODE 5: gelu->fp8 (split-K A)   6: f32 out                 7: fp8 out x16
template<int MODE>
__global__ __launch_bounds__(256, 3) void gemm128f8(
    const u8* __restrict__ A, const u8* __restrict__ A2, int splitK,
    const u8* __restrict__ B, void* __restrict__ C,
    const int* __restrict__ dst, const int* __restrict__ cnt,
    int Ksz, int lda, int ldb, int ldc, int ntm,
    size_t sA, size_t sB, size_t sC, unsigned sclA, unsigned sclB)
{
  __shared__ char smem[32768];
  int e = blockIdx.y;
  int nwgx = gridDim.x, bid0 = blockIdx.x;
  int q = nwgx >> 3, r = nwgx & 7;
  int xcd = bid0 & 7, lo2 = bid0 >> 3;
  int bid = (xcd < r ? xcd * (q + 1) : r * (q + 1) + (xcd - r) * q) + lo2;
  int tm = bid % ntm, tn = bid / ntm;
  if (MODE == 1 || MODE == 2) {
    if (tm * 128 >= cnt[e]) return;
  }
  const u8* Ae = A + (size_t)e * sA;
  const u8* Be = B + (size_t)e * sB;
  long long bdelta = (const char*)A2 - (const char*)Ae;
  int tid = threadIdx.x, wv = tid >> 6, ln = tid & 63;
  int lnl = ln & 15, lnh = ln >> 4;

  const u8* aP[4]; const u8* bP[4];
  unsigned aL[4], bL[4];
  #pragma unroll
  for (int i = 0; i < 4; ++i) {
    int row = i * 32 + wv * 8 + (ln >> 3);
    int c = (ln & 7) ^ (row & 7);
    int cp = ((c & 3) << 1) | (c >> 2);
    aP[i] = Ae + (size_t)(tm * 128 + row) * lda + cp * 16;
    int brow;
    if (MODE == 1) {
      brow = (row < 64) ? (tn * 64 + row) : (Hv + tn * 64 + (row - 64));
    } else {
      brow = tn * 128 + row;
    }
    bP[i] = Be + (size_t)brow * ldb + cp * 16;
    aL[i] = i * 4096 + wv * 1024;
    bL[i] = 16384 + i * 4096 + wv * 1024;
  }

  int arow0 = wv * 32 + lnl;
  int ksw0 = (lnh << 4);
  int ksw1 = 64 + (lnh << 4);

  f32x4 acc[2][8];
  #pragma unroll
  for (int m = 0; m < 2; ++m)
    #pragma unroll
    for (int n = 0; n < 8; ++n) acc[m][n] = (f32x4){0.f, 0.f, 0.f, 0.f};

  for (int k0 = 0; k0 < Ksz; k0 += 128) {
    long long kbA;
    if (MODE == 5 && k0 >= splitK) kbA = bdelta + (long long)(k0 - splitK);
    else kbA = (long long)k0;
    #pragma unroll
    for (int i = 0; i < 4; ++i) gload16(aP[i] + kbA, smem + aL[i]);
    #pragma unroll
    for (int i = 0; i < 4; ++i) gload16(bP[i] + (size_t)k0, smem + bL[i]);
    __syncthreads();

    i32x8 af[2];
    #pragma unroll
    for (int mi = 0; mi < 2; ++mi) {
      int row = arow0 + mi * 16;
      int swz = (row & 7) << 4;
      *(i32x4*)&af[mi] = *(const i32x4*)(smem + row * 128 + (ksw0 ^ swz));
      *((i32x4*)&af[mi] + 1) = *(const i32x4*)(smem + row * 128 + (ksw1 ^ swz));
    }
    #pragma unroll
    for (int n = 0; n < 8; ++n) {
      int row = n * 16 + lnl;
      int swz = (row & 7) << 4;
      i32x8 bf;
      *(i32x4*)&bf = *(const i32x4*)(smem + 16384 + row * 128 + (ksw0 ^ swz));
      *((i32x4*)&bf + 1) = *(const i32x4*)(smem + 16384 + row * 128 + (ksw1 ^ swz));
      acc[0][n] = __builtin_amdgcn_mfma_scale_f32_16x16x128_f8f6f4(
          af[0], bf, acc[0][n], 0, 0, 0, sclA, 0, sclB);
      acc[1][n] = __builtin_amdgcn_mfma_scale_f32_16x16x128_f8f6f4(
          af[1], bf, acc[1][n], 0, 0, 0, sclA, 0, sclB);
    }
    __syncthreads();
  }

  int rbase = tm * 128 + wv * 32 + (lnh << 2);
  if (MODE == 1) {
    u8* Cp = (u8*)C + (size_t)e * sC;
    #pragma unroll
    for (int mi = 0; mi < 2; ++mi)
      #pragma unroll
      for (int n = 0; n < 4; ++n) {
        int col = tn * 64 + n * 16 + lnl;
        #pragma unroll
        for (int v = 0; v < 4; ++v) {
          float g = acc[mi][n][v];
          float u = acc[mi][n + 4][v];
          float sg = g / (1.f + __expf(-g));
          Cp[(size_t)(rbase + mi * 16 + v) * ldc + col] = f2e4h(sg * u);
        }
      }
  } else if (MODE == 2) {
    u8* Cq = (u8*)C;
    #pragma unroll
    for (int mi = 0; mi < 2; ++mi)
      #pragma unroll
      for (int v = 0; v < 4; ++v) {
        int gr = rbase + mi * 16 + v;
        int i = dst[e * CAPv + gr];
        if (i >= 0) {
          #pragma unroll
          for (int n = 0; n < 8; ++n) {
            int col = tn * 128 + n * 16 + lnl;
            Cq[(size_t)i * Dv + col] = f2e4h(acc[mi][n][v]);
          }
        }
      }
  } else if (MODE == 4) {
    u8* Cp = (u8*)C;
    #pragma unroll
    for (int mi = 0; mi < 2; ++mi)
      #pragma unroll
      for (int n = 0; n < 8; ++n) {
        int col = tn * 128 + n * 16 + lnl;
        #pragma unroll
        for (int v = 0; v < 4; ++v)
          Cp[(size_t)(rbase + mi * 16 + v) * ldc + col] = f2e4h(acc[mi][n][v]);
      }
  } else if (MODE == 5) {
    u8* Cp = (u8*)C;
    #pragma unroll
    for (int mi = 0; mi < 2; ++mi)
      #pragma unroll
      for (int n = 0; n < 8; ++n) {
        int col = tn * 128 + n * 16 + lnl;
        #pragma unroll
        for (int v = 0; v < 4; ++v) {
          float xg = acc[mi][n][v];
          float gl = 0.5f * xg * (1.f + erff(xg * 0.70710678118654752f));
          Cp[(size_t)(rbase + mi * 16 + v) * ldc + col] = f2e4h(gl);
        }
      }
  } else if (MODE == 7) {
    u8* Cp = (u8*)C;
    #pragma unroll
    for (int mi = 0; mi < 2; ++mi)
      #pragma unroll
      for (int n = 0; n < 8; ++n) {
        int col = tn * 128 + n * 16 + lnl;
        #pragma unroll
        for (int v = 0; v < 4; ++v)
          Cp[(size_t)(rbase + mi * 16 + v) * ldc + col] = f2e4h(acc[mi][n][v] * 16.f);
      }
  } else {
    float* Cp = (float*)C;
    #pragma unroll
    for (int mi = 0; mi < 2; ++mi)
      #pragma unroll
      for (int n = 0; n < 8; ++n) {
        int col = tn * 128 + n * 16 + lnl;
        #pragma unroll
        for (int v = 0; v < 4; ++v)
          Cp[(size_t)(rbase + mi * 16 + v) * ldc + col] = acc[mi][n][v];
      }
  }
}

// ---------------- scores + masked softmax + Cmsg ----------------
__global__ __launch_bounds__(256) void scores8_kernel(
    const u8* __restrict__ MQ, const u8* __restrict__ SEL8,
    const int* __restrict__ keep, u8* __restrict__ Cmsg)
{
  int wv = threadIdx.x >> 6, ln = threadIdx.x & 63;
  int n = blockIdx.x * 4 + wv;
  const u8* m0 = MQ + (size_t)(2 * n) * 2048;
  const u8* m1 = MQ + (size_t)(2 * n + 1) * 2048;
  const u8* t0 = m0 + 1024;
  const u8* t1 = m1 + 1024;
  const u8* s0p = SEL8 + (size_t)(2 * n) * 1024;
  const u8* s1p = SEL8 + (size_t)(2 * n + 1) * 1024;
  int d0 = ln * 16;
  float a0[16], a1[16], b0[16], b1[16];
  dec16(t0 + d0, a0); dec16(t1 + d0, a1);
  dec16(s0p + d0, b0); dec16(s1p + d0, b1);
  float s00 = 0, s01 = 0, s10 = 0, s11 = 0;
  #pragma unroll
  for (int t = 0; t < 16; ++t) {
    s00 += a0[t] * b0[t]; s01 += a0[t] * b1[t];
    s10 += a1[t] * b0[t]; s11 += a1[t] * b1[t];
  }
  #pragma unroll
  for (int off = 32; off >= 1; off >>= 1) {
    s00 += __shfl_xor(s00, off, 64);
    s01 += __shfl_xor(s01, off, 64);
    s10 += __shfl_xor(s10, off, 64);
    s11 += __shfl_xor(s11, off, 64);
  }
  const float inv = 0.03125f;
  int kp0 = keep[2 * n], kp1 = keep[2 * n + 1];
  float A00, A01, A10, A11;
  {
    float v0 = kp0 ? s00 * inv : -1e9f;
    float v1 = (kp0 && kp1) ? s01 * inv : -1e9f;
    float mx = fmaxf(v0, v1);
    float e0 = expf(v0 - mx), e1 = expf(v1 - mx);
    float den = e0 + e1;
    float a0v = kp0 ? e0 / den : 0.f;
    float a1v = (kp0 && kp1) ? e1 / den : 0.f;
    float s = fmaxf(a0v + a1v, 1e-12f);
    A00 = a0v / s; A01 = a1v / s;
  }
  {
    float v0 = (kp1 && kp0) ? s10 * inv : -1e9f;
    float v1 = kp1 ? s11 * inv : -1e9f;
    float mx = fmaxf(v0, v1);
    float e0 = expf(v0 - mx), e1 = expf(v1 - mx);
    float den = e0 + e1;
    float a0v = (kp1 && kp0) ? e0 / den : 0.f;
    float a1v = kp1 ? e1 / den : 0.f;
    float s = fmaxf(a0v + a1v, 1e-12f);
    A10 = a0v / s; A11 = a1v / s;
  }
  float f0[16], f1[16];
  dec16(m0 + d0, f0); dec16(m1 + d0, f1);
  u8* c0 = Cmsg + (size_t)(2 * n) * 1024 + d0;
  u8* c1 = Cmsg + (size_t)(2 * n + 1) * 1024 + d0;
  #pragma unroll
  for (int j = 0; j < 4; ++j) {
    int t = j * 4;
    *(unsigned*)(c0 + j * 4) = cvtpk4(
        A00 * f0[t] + A01 * f1[t],     A00 * f0[t+1] + A01 * f1[t+1],
        A00 * f0[t+2] + A01 * f1[t+2], A00 * f0[t+3] + A01 * f1[t+3]);
    *(unsigned*)(c1 + j * 4) = cvtpk4(
        A10 * f0[t] + A11 * f1[t],     A10 * f0[t+1] + A11 * f1[t+1],
        A10 * f0[t+2] + A11 * f1[t+2], A10 * f0[t+3] + A11 * f1[t+3]);
  }
}

// ---------------- combine2: FCAT = [sum w_k sel_k | sum w_k gelu_k] fp8 ----------------
__global__ __launch_bounds__(256) void combine2_kernel(
    const u8* __restrict__ sel8, const u8* __restrict__ g8,
    const int* __restrict__ keep, const float* __restrict__ tkprob,
    u8* __restrict__ fcat)
{
  int n = blockIdx.x;
  int t = threadIdx.x;
  float kp0 = keep[2 * n] ? 1.f : 0.f, kp1 = keep[2 * n + 1] ? 1.f : 0.f;
  float p0 = tkprob[2 * n] * kp0, p1 = tkprob[2 * n + 1] * kp1;
  float s = fmaxf(p0 + p1, 1e-12f);
  float w0 = p0 / s, w1 = p1 / s;
  unsigned a = *(const unsigned*)(sel8 + (size_t)(2 * n) * 1024 + t * 4);
  unsigned b = *(const unsigned*)(sel8 + (size_t)(2 * n + 1) * 1024 + t * 4);
  float fa[4], fb[4];
  dec4(a, fa); dec4(b, fb);
  *(unsigned*)(fcat + (size_t)n * 3072 + t * 4) = cvtpk4(
      w0 * fa[0] + w1 * fb[0], w0 * fa[1] + w1 * fb[1],
      w0 * fa[2] + w1 * fb[2], w0 * fa[3] + w1 * fb[3]);
  const u8* ga = g8 + (size_t)(2 * n) * 2048 + t * 8;
  const u8* gb = g8 + (size_t)(2 * n + 1) * 2048 + t * 8;
  #pragma unroll
  for (int h = 0; h < 2; ++h) {
    unsigned xa = *(const unsigned*)(ga + h * 4);
    unsigned xb = *(const unsigned*)(gb + h * 4);
    dec4(xa, fa); dec4(xb, fb);
    *(unsigned*)(fcat + (size_t)n * 3072 + 1024 + t * 8 + h * 4) = cvtpk4(
        w0 * fa[0] + w1 * fb[0], w0 * fa[1] + w1 * fb[1],
        w0 * fa[2] + w1 * fb[2], w0 * fa[3] + w1 * fb[3]);
  }
}

extern "C" void kernel_launch(void* const* d_in, const int* in_sizes, int n_in,
                              void* d_out, int out_size, void* d_ws, size_t ws_size,
                              hipStream_t stream) {
  const float* x      = (const float*)d_in[0];
  const float* gate_w = (const float*)d_in[1];
  const float* w13    = (const float*)d_in[2];
  const float* w2     = (const float*)d_in[3];
  const float* msg_w  = (const float*)d_in[4];
  const float* q_w    = (const float*)d_in[5];
  const float* k_w    = (const float*)d_in[6];
  const float* upd_w1 = (const float*)d_in[7];
  const float* upd_w2 = (const float*)d_in[8];
  const float* o_w    = (const float*)d_in[9];
  float* out = (float*)d_out;
  float* outAux = out + (size_t)Nv * Dv;
  float* outIdx = outAux + 1;

  char* ws = (char*)d_ws;
  const size_t MBc = 1ull << 20;
  int*   tkidx  = (int*)(ws + 0);
  float* tkprob = (float*)(ws + 32768);
  int*   keepA  = (int*)(ws + 65536);
  int*   dstNK  = (int*)(ws + 98304);
  float* red    = (float*)(ws + 143360);
  int*   cntA   = (int*)(ws + 147456);
  u8*  BUF8  = (u8*)(ws + 1 * MBc);
  u8*  ACT8  = (u8*)(ws + 12 * MBc);
  u8*  W13B8 = (u8*)(ws + 41 * MBc);
  u8*  M8s   = (u8*)(ws + 85 * MBc);
  u8*  Q8s   = (u8*)(ws + 86 * MBc);
  u8*  K8T   = (u8*)(ws + 87 * MBc);
  u8*  W2B8r = (u8*)(ws + 88 * MBc);
  u8*  U28s  = (u8*)(ws + 110 * MBc);
  u8*  MTB8  = (u8*)(ws + 112 * MBc);
  u8*  WCAT8 = (u8*)(ws + 114 * MBc);
  u8*  P38   = (u8*)(ws + 117 * MBc);
  u8*  SEL8  = (u8*)(ws + 136 * MBc);
  u8*  UPD1B8= (u8*)(ws + 149 * MBc);
  u8*  FCAT8 = (u8*)(ws + 160 * MBc);
  u8*  MQ8   = (u8*)(ws + 1 * MBc);
  u8*  CMSG8 = (u8*)(ws + 18 * MBc);
  u8*  G1B8  = (u8*)(ws + 27 * MBc);

  hipMemsetAsync(red, 0, 68, stream);
  hipMemsetAsync(dstNK, 0xFF, Ev * CAPv * 4, stream);
  hipMemsetAsync(SEL8, 0, (size_t)NKv * Dv, stream);

  router_kernel<<<Nv / 4, 256, 0, stream>>>(x, gate_w, tkidx, tkprob, red, outIdx);
  rank_kernel<<<1, 256, 0, stream>>>(tkidx, keepA, dstNK, cntA, red, outAux);
  pack8_kernel<<<(Ev * CAPv) / 4, 256, 0, stream>>>(x, dstNK, BUF8);

  WTab T;
  T.in[0]=w13;    T.out[0]=W13B8; T.R[0]=Dv;   T.C[0]=TH2v; T.ldo[0]=Dv;   T.nxy[0]=352; T.nx[0]=44;
  T.in[1]=w2;     T.out[1]=W2B8r; T.R[1]=Hv;   T.C[1]=Dv;   T.ldo[1]=Hv;   T.nxy[1]=176; T.nx[1]=8;
  T.in[2]=upd_w1; T.out[2]=UPD1B8;T.R[2]=2048; T.C[2]=2048; T.ldo[2]=2048; T.nxy[2]=256; T.nx[2]=16;
  T.in[3]=msg_w;  T.out[3]=MTB8;  T.R[3]=Dv;   T.C[3]=Dv;   T.ldo[3]=Dv;   T.nxy[3]=64;  T.nx[3]=8;
  T.in[4]=o_w;    T.out[4]=WCAT8; T.R[4]=Dv;   T.C[4]=Dv;   T.ldo[4]=3072; T.nxy[4]=64;  T.nx[4]=8;
  T.in[5]=k_w;    T.out[5]=K8T;   T.R[5]=Dv;   T.C[5]=Dv;   T.ldo[5]=Dv;   T.nxy[5]=64;  T.nx[5]=8;
  T.in[6]=msg_w;  T.out[6]=M8s;   T.nx[6]=0; T.R[6]=0; T.C[6]=0; T.ldo[6]=0; T.nxy[6]=0;
  T.in[7]=q_w;    T.out[7]=Q8s;   T.nx[7]=0; T.R[7]=0; T.C[7]=0; T.ldo[7]=0; T.nxy[7]=0;
  T.in[8]=upd_w2; T.out[8]=U28s;  T.nx[8]=0; T.R[8]=0; T.C[8]=0; T.ldo[8]=0; T.nxy[8]=0;
  T.start[0]=0; T.start[1]=2816; T.start[2]=4224; T.start[3]=4480;
  T.start[4]=4544; T.start[5]=4608; T.start[6]=4672; T.start[7]=5696; T.start[8]=6720;
  wprep_kernel<<<8768, 256, 0, stream>>>(T);

  // G1: MX-fp8 SwiGLU -> ACT8 (early-exit via cntA)
  gemm128f8<1><<<dim3((CAPv / 128) * (Hv / 64), Ev), 256, 0, stream>>>(
      BUF8, BUF8, 1 << 30, W13B8, (void*)ACT8, nullptr, cntA,
      Dv, Dv, Dv, Hv, CAPv / 128,
      (size_t)CAPv * Dv, (size_t)TH2v * Dv, (size_t)CAPv * Hv, 0x7F7F7F7Fu, 0x7B7B7B7Bu);

  // W_s^T = (msg@k) @ q^T  (MODE 7: fp8 x16 out, no conversion round-trips)
  gemm128f8<7><<<dim3(64, 1), 256, 0, stream>>>(
      M8s, M8s, 1 << 30, K8T, (void*)P38, nullptr, nullptr,
      Dv, Dv, Dv, Dv, 8, 0, 0, 0, 0x7B7B7B7Bu, 0x7B7B7B7Bu);
  gemm128f8<7><<<dim3(64, 1), 256, 0, stream>>>(
      P38, P38, 1 << 30, Q8s, (void*)(MTB8 + (size_t)Dv * Dv), nullptr, nullptr,
      Dv, Dv, Dv, Dv, 8, 0, 0, 0, 0x7B7B7B7Bu, 0x7B7B7B7Bu);
  // T2^T = o_w^T @ upd_w2^T -> WCAT8+1024 (ldc 3072)
  gemm128f8<7><<<dim3(128, 1), 256, 0, stream>>>(
      WCAT8, WCAT8, 1 << 30, U28s, (void*)(WCAT8 + 1024), nullptr, nullptr,
      Dv, 3072, Dv, 3072, 8, 0, 0, 0, 0x7B7B7B7Bu, 0x7B7B7B7Bu);

  // G2: MX-fp8 GEMM + scatter -> SEL8 (early-exit via cntA)
  gemm128f8<2><<<dim3((CAPv / 128) * (Dv / 128), Ev), 256, 0, stream>>>(
      ACT8, ACT8, 1 << 30, W2B8r, (void*)SEL8, dstNK, cntA,
      Hv, Hv, Hv, Dv, CAPv / 128,
      (size_t)CAPv * Hv, (size_t)Dv * Hv, 0, 0x7F7F7F7Fu, 0x7B7B7B7Bu);

  // collaboration: fused [M|T] GEMM, then scores
  gemm128f8<4><<<dim3(64 * 16, 1), 256, 0, stream>>>(
      SEL8, SEL8, 1 << 30, MTB8, (void*)MQ8, nullptr, nullptr,
      Dv, Dv, Dv, 2048, 64, 0, 0, 0, 0x7F7F7F7Fu, 0x7B7B7B7Bu);
  scores8_kernel<<<Nv / 4, 256, 0, stream>>>(MQ8, SEL8, keepA, CMSG8);

  // update MLP: gelu([SEL8|CMSG8] @ upd_w1) -> G1B8
  gemm128f8<5><<<dim3(64 * 16, 1), 256, 0, stream>>>(
      SEL8, CMSG8, Dv, UPD1B8, (void*)G1B8, nullptr, nullptr,
      2048, Dv, 2048, 2048, 64, 0, 0, 0, 0x7F7F7F7Fu, 0x7B7B7B7Bu);

  // FCAT = [sum w sel | sum w gelu], final fused GEMM -> out (f32)
  combine2_kernel<<<Nv, 256, 0, stream>>>(SEL8, G1B8, keepA, tkprob, FCAT8);
  gemm128f8<6><<<dim3(32 * 8, 1), 256, 0, stream>>>(
      FCAT8, FCAT8, 1 << 30, WCAT8, (void*)out, nullptr, nullptr,
      3072, 3072, 3072, Dv, 32, 0, 0, 0, 0x7F7F7F7Fu, 0x7B7B7B7Bu);

  (void)in_sizes; (void)n_in; (void)out_size; (void)ws_size;
}